// Round 4
// baseline (227.994 us; speedup 1.0000x reference)
//
#include <hip/hip_runtime.h>

#define ALPHA 0.1f
#define NUM_CLASSES 10

typedef __attribute__((ext_vector_type(8))) short bf16x8;
typedef __attribute__((ext_vector_type(4))) float f32x4;

// ---------------------------------------------------------------------------
// ws layout (bytes):
//   loss  @ 0   : float[1]
//   counts@ 4   : uint[100]
// (zeroed each launch via hipMemsetAsync)
//
// ROUND 14: latency attack on the R13 skeleton (R13==R10==~70us showed the
// floor is dependency latency, not barriers/atomics):
//  A. __launch_bounds__(512,6): LDS (46KB) caps residency at 3 blocks/CU =
//     24 waves = 6 waves/EU regardless; (512,4)'s 64-VGPR squeeze bought
//     nothing.  85-VGPR budget gives the scheduler room to pipeline
//     b-frag reads across pt iterations.
//  B. grid=768: exactly 3 blocks/CU, all resident at t=0 (grid=1024 left a
//     256-block dispatch tail behind 768 residency slots).
//  C. MFMA chains split by k-half: accA (preloaded with x2+c2+1) takes the
//     k0-31 products, accB (zero) takes k32-63; merged with 4 adds.  Dep
//     depth 6 -> 3, and 4 independent chains per pt.
//  D. one-round gather reductions: 3 parallel __shfl + 2-deep tree instead
//     of two sequential shfl_xor+add rounds (x2, swe, swd, best).  Only
//     lanes q==0 need the result; gather from r+16/r+32/r+48.
//  E. epilogue sums tree-shaped (parallel trans + independent fma trees).
//  F. finalize: 100 threads load counts in parallel into LDS; thread 0
//     runs the greedy from LDS (was: thread 0 serially loading 101 global
//     words, ~10-30us).
// Numerics: fp32 summation reorder only (R11/R12 proved reorder passes).
// ---------------------------------------------------------------------------

__device__ __forceinline__ unsigned pack2(float a, float b) {
    // bf16(a) lo16 | bf16(b) hi16 (truncation -> exact Dekker hi split)
    return (__float_as_uint(b) & 0xFFFF0000u) | (__float_as_uint(a) >> 16);
}
__device__ __forceinline__ float truncbf(float a) {
    return __uint_as_float(__float_as_uint(a) & 0xFFFF0000u);
}
__device__ __forceinline__ float gsum4(float v, int s1, int s2, int s3) {
    // valid in lanes 0-15 only (gather from r+16, r+32, r+48)
    const float a = __shfl(v, s1);
    const float b = __shfl(v, s2);
    const float c = __shfl(v, s3);
    return (v + a) + (b + c);
}
__device__ __forceinline__ unsigned gmin4(unsigned v, int s1, int s2, int s3) {
    const unsigned a = (unsigned)__shfl((int)v, s1);
    const unsigned b = (unsigned)__shfl((int)v, s2);
    const unsigned c = (unsigned)__shfl((int)v, s3);
    return min(min(v, a), min(b, c));
}

// 512 threads = 8 waves. Wave w owns centers [w*32, w*32+32) (M dim) and
// stages points [t*128 + w*16, +16) (N dim).  Lane: r = l&15 (point row),
// q = l>>4 (k-group of 8 floats).
__global__ __launch_bounds__(512, 6) void dist_kernel(
    const float* __restrict__ x,
    const int*   __restrict__ y,
    const float* __restrict__ centers,
    float* __restrict__ loss_acc,
    unsigned int* __restrict__ counts,
    int NT)
{
    // bstage[pt][f][lane] : 16 B per lane, contiguous-lane layout (b128)
    __shared__ __align__(16) char bstage[8 * 4 * 64 * 16];   // 32 KB
    __shared__ float x2s[128];
    __shared__ float c2s[256];
    __shared__ float    comb_swe[8][128];    // 4 KB
    __shared__ float    comb_swd[8][128];    // 4 KB
    __shared__ unsigned comb_best[8][128];   // 4 KB
    __shared__ unsigned counts_l[100];

    const int tid  = threadIdx.x;
    const int w    = tid >> 6;     // wave id = center group (32 centers)
    const int lane = tid & 63;
    const int q    = lane >> 4;    // k-group
    const int r    = lane & 15;    // point row within subtile
    const int s1 = r + 16, s2 = r + 32, s3 = r + 48;   // gather partners

    if (tid < 100) counts_l[tid] = 0u;

    // ---- startup: center norms (one center per thread) ----
    if (tid < 256) {
        const float4* crow = (const float4*)(centers + tid * 64);
        float s = 0.f;
#pragma unroll
        for (int j = 0; j < 16; ++j) {
            float4 v = crow[j];
            s = fmaf(v.x, v.x, s); s = fmaf(v.y, v.y, s);
            s = fmaf(v.z, v.z, s); s = fmaf(v.w, v.w, s);
        }
        c2s[tid] = s;
    }

    // ---- startup: this wave's center A-frags, PRE-SCALED by -2 ----
    // af[ct][f]; f: 0=mh k0-31, 1=mh k32-63, 2=ml k0-31, 3=ml k32-63
    bf16x8 af[2][4];
#pragma unroll
    for (int ct = 0; ct < 2; ++ct) {
        const int row = w * 32 + ct * 16 + r;
        const float4* C = (const float4*)(centers + (size_t)row * 64);
        float4 v0 = C[q * 2], v1 = C[q * 2 + 1];       // k = q*8 .. q*8+7
        float4 v2 = C[8 + q * 2], v3 = C[9 + q * 2];   // k = 32+q*8 ..
        float4 m0 = make_float4(-2.f * v0.x, -2.f * v0.y, -2.f * v0.z, -2.f * v0.w);
        float4 m1 = make_float4(-2.f * v1.x, -2.f * v1.y, -2.f * v1.z, -2.f * v1.w);
        float4 m2 = make_float4(-2.f * v2.x, -2.f * v2.y, -2.f * v2.z, -2.f * v2.w);
        float4 m3 = make_float4(-2.f * v3.x, -2.f * v3.y, -2.f * v3.z, -2.f * v3.w);
        union { bf16x8 v; unsigned u[4]; } h0, h1, l0, l1;
        h0.u[0] = pack2(m0.x, m0.y); h0.u[1] = pack2(m0.z, m0.w);
        h0.u[2] = pack2(m1.x, m1.y); h0.u[3] = pack2(m1.z, m1.w);
        h1.u[0] = pack2(m2.x, m2.y); h1.u[1] = pack2(m2.z, m2.w);
        h1.u[2] = pack2(m3.x, m3.y); h1.u[3] = pack2(m3.z, m3.w);
        l0.u[0] = pack2(m0.x - truncbf(m0.x), m0.y - truncbf(m0.y));
        l0.u[1] = pack2(m0.z - truncbf(m0.z), m0.w - truncbf(m0.w));
        l0.u[2] = pack2(m1.x - truncbf(m1.x), m1.y - truncbf(m1.y));
        l0.u[3] = pack2(m1.z - truncbf(m1.z), m1.w - truncbf(m1.w));
        l1.u[0] = pack2(m2.x - truncbf(m2.x), m2.y - truncbf(m2.y));
        l1.u[1] = pack2(m2.z - truncbf(m2.z), m2.w - truncbf(m2.w));
        l1.u[2] = pack2(m3.x - truncbf(m3.x), m3.y - truncbf(m3.y));
        l1.u[3] = pack2(m3.z - truncbf(m3.z), m3.w - truncbf(m3.w));
        af[ct][0] = h0.v; af[ct][1] = h1.v; af[ct][2] = l0.v; af[ct][3] = l1.v;
    }

    // ---- prefetch first tile's x (every wave stages its own subtile) ----
    float4 pv0, pv1, pv2, pv3;
    {
        const int row = blockIdx.x * 128 + w * 16 + r;
        const float4* X = (const float4*)(x + (size_t)row * 64);
        pv0 = X[q * 2]; pv1 = X[q * 2 + 1];
        pv2 = X[8 + q * 2]; pv3 = X[9 + q * 2];
    }

    __syncthreads();   // startup: c2s / counts_l visible

    // this lane's 8 center norms + 1: u = (x2 + c2 + 1) + (-2 x.c)
    float c2r1[2][4];
#pragma unroll
    for (int ct = 0; ct < 2; ++ct) {
        float4 v = *(const float4*)(c2s + w * 32 + ct * 16 + q * 4);
        c2r1[ct][0] = v.x + 1.f; c2r1[ct][1] = v.y + 1.f;
        c2r1[ct][2] = v.z + 1.f; c2r1[ct][3] = v.w + 1.f;
    }

    float loss_local = 0.f;

    for (int t = blockIdx.x; t < NT; t += gridDim.x) {
        // ---- y prefetch for this tile's combine (latency spans the tile) ----
        int ylab = 0;
        if (tid < 128) ylab = y[t * 128 + tid];

        // ---- stage: every wave converts its subtile from prefetched regs ----
        {
            float4 v0 = pv0, v1 = pv1, v2 = pv2, v3 = pv3;

            // issue next tile's loads immediately (latency hidden by MFMA phase)
            const int tn = t + gridDim.x;
            if (tn < NT) {
                const int row = tn * 128 + w * 16 + r;
                const float4* X = (const float4*)(x + (size_t)row * 64);
                pv0 = X[q * 2]; pv1 = X[q * 2 + 1];
                pv2 = X[8 + q * 2]; pv3 = X[9 + q * 2];
            }

            float p = v0.x * v0.x;
            p = fmaf(v0.y, v0.y, p); p = fmaf(v0.z, v0.z, p); p = fmaf(v0.w, v0.w, p);
            p = fmaf(v1.x, v1.x, p); p = fmaf(v1.y, v1.y, p); p = fmaf(v1.z, v1.z, p); p = fmaf(v1.w, v1.w, p);
            p = fmaf(v2.x, v2.x, p); p = fmaf(v2.y, v2.y, p); p = fmaf(v2.z, v2.z, p); p = fmaf(v2.w, v2.w, p);
            p = fmaf(v3.x, v3.x, p); p = fmaf(v3.y, v3.y, p); p = fmaf(v3.z, v3.z, p); p = fmaf(v3.w, v3.w, p);
            p = gsum4(p, s1, s2, s3);
            if (q == 0) x2s[w * 16 + r] = p;

            union { bf16x8 v; uint4 u4; unsigned u[4]; } h0, h1, l0, l1;
            h0.u[0] = pack2(v0.x, v0.y); h0.u[1] = pack2(v0.z, v0.w);
            h0.u[2] = pack2(v1.x, v1.y); h0.u[3] = pack2(v1.z, v1.w);
            h1.u[0] = pack2(v2.x, v2.y); h1.u[1] = pack2(v2.z, v2.w);
            h1.u[2] = pack2(v3.x, v3.y); h1.u[3] = pack2(v3.z, v3.w);
            l0.u[0] = pack2(v0.x - truncbf(v0.x), v0.y - truncbf(v0.y));
            l0.u[1] = pack2(v0.z - truncbf(v0.z), v0.w - truncbf(v0.w));
            l0.u[2] = pack2(v1.x - truncbf(v1.x), v1.y - truncbf(v1.y));
            l0.u[3] = pack2(v1.z - truncbf(v1.z), v1.w - truncbf(v1.w));
            l1.u[0] = pack2(v2.x - truncbf(v2.x), v2.y - truncbf(v2.y));
            l1.u[1] = pack2(v2.z - truncbf(v2.z), v2.w - truncbf(v2.w));
            l1.u[2] = pack2(v3.x - truncbf(v3.x), v3.y - truncbf(v3.y));
            l1.u[3] = pack2(v3.z - truncbf(v3.z), v3.w - truncbf(v3.w));
            *(uint4*)(bstage + (((w * 4 + 0) * 64 + lane) << 4)) = h0.u4;
            *(uint4*)(bstage + (((w * 4 + 1) * 64 + lane) << 4)) = h1.u4;
            *(uint4*)(bstage + (((w * 4 + 2) * 64 + lane) << 4)) = l0.u4;
            *(uint4*)(bstage + (((w * 4 + 3) * 64 + lane) << 4)) = l1.u4;
        }
        __syncthreads();   // barA: frags + x2s visible; prev combine done

        // ---- per 16-point subtile: split-chain MFMA then tree epilogue ----
#pragma unroll
        for (int pt = 0; pt < 8; ++pt) {
            union { uint4 u4; bf16x8 v; } b0, b1, b2, b3;
            b0.u4 = *(const uint4*)(bstage + (((pt * 4 + 0) * 64 + lane) << 4));
            b1.u4 = *(const uint4*)(bstage + (((pt * 4 + 1) * 64 + lane) << 4));
            b2.u4 = *(const uint4*)(bstage + (((pt * 4 + 2) * 64 + lane) << 4));
            b3.u4 = *(const uint4*)(bstage + (((pt * 4 + 3) * 64 + lane) << 4));
            const float x2p = x2s[pt * 16 + r];

            f32x4 acc[2];
#pragma unroll
            for (int ct = 0; ct < 2; ++ct) {
                f32x4 aA;   // k0-31 products, preloaded with x2+c2+1
                aA[0] = x2p + c2r1[ct][0]; aA[1] = x2p + c2r1[ct][1];
                aA[2] = x2p + c2r1[ct][2]; aA[3] = x2p + c2r1[ct][3];
                f32x4 aB = {0.f, 0.f, 0.f, 0.f};   // k32-63 products
                aA = __builtin_amdgcn_mfma_f32_16x16x32_bf16(af[ct][0], b0.v, aA, 0, 0, 0); // mh.xh lo
                aB = __builtin_amdgcn_mfma_f32_16x16x32_bf16(af[ct][1], b1.v, aB, 0, 0, 0); // mh.xh hi
                aA = __builtin_amdgcn_mfma_f32_16x16x32_bf16(af[ct][2], b0.v, aA, 0, 0, 0); // ml.xh lo
                aB = __builtin_amdgcn_mfma_f32_16x16x32_bf16(af[ct][3], b1.v, aB, 0, 0, 0); // ml.xh hi
                aA = __builtin_amdgcn_mfma_f32_16x16x32_bf16(af[ct][0], b2.v, aA, 0, 0, 0); // mh.xl lo
                aB = __builtin_amdgcn_mfma_f32_16x16x32_bf16(af[ct][1], b3.v, aB, 0, 0, 0); // mh.xl hi
                acc[ct] = aA + aB;
            }

            float swe_c[2], swd_c[2];
            unsigned bst_c[2];
#pragma unroll
            for (int ct = 0; ct < 2; ++ct) {
                const float u0 = acc[ct][0], u1 = acc[ct][1];
                const float u2 = acc[ct][2], u3 = acc[ct][3];
                const unsigned kb = (unsigned)(w * 32 + ct * 16 + q * 4);
                const unsigned p0 = (__float_as_uint(u0) & 0xFFFFFF00u) | kb;
                const unsigned p1 = (__float_as_uint(u1) & 0xFFFFFF00u) | (kb + 1);
                const unsigned p2 = (__float_as_uint(u2) & 0xFFFFFF00u) | (kb + 2);
                const unsigned p3 = (__float_as_uint(u3) & 0xFFFFFF00u) | (kb + 3);
                bst_c[ct] = min(min(p0, p1), min(p2, p3));
                const float g0 = exp2f(-ALPHA * __log2f(u0));
                const float g1 = exp2f(-ALPHA * __log2f(u1));
                const float g2 = exp2f(-ALPHA * __log2f(u2));
                const float g3 = exp2f(-ALPHA * __log2f(u3));
                swe_c[ct] = (g0 + g1) + (g2 + g3);
                float t0 = g0 * u0; t0 = fmaf(g1, u1, t0);
                float t1 = g2 * u2; t1 = fmaf(g3, u3, t1);
                swd_c[ct] = t0 + t1;
            }
            float swe = swe_c[0] + swe_c[1];
            float swdu = swd_c[0] + swd_c[1];
            unsigned best = min(bst_c[0], bst_c[1]);

            // one-round gather reduce over q (4 lanes share point pt*16+r)
            swe  = gsum4(swe, s1, s2, s3);
            swdu = gsum4(swdu, s1, s2, s3);
            best = gmin4(best, s1, s2, s3);
            if (q == 0) {
                comb_swe[w][pt * 16 + r]  = swe;
                comb_swd[w][pt * 16 + r]  = swdu;
                comb_best[w][pt * 16 + r] = best;
            }
        }
        __syncthreads();   // barB: all groups' partials visible

        // ---- combine across 8 center groups (waves 0-1, one point each) ----
        if (tid < 128) {
            float SWE = comb_swe[0][tid], SWD = comb_swd[0][tid];
            unsigned BEST = comb_best[0][tid];
#pragma unroll
            for (int g = 1; g < 8; ++g) {
                SWE += comb_swe[g][tid];
                SWD += comb_swd[g][tid];
                BEST = min(BEST, comb_best[g][tid]);
            }
            loss_local += SWD / SWE - 1.f;   // Sum w*d / Sum w  ==  swdu/swe - 1
            const unsigned bk = BEST & 0xFFu;
            if (bk < NUM_CLASSES) {
                atomicAdd(&counts_l[bk * NUM_CLASSES + ylab], 1u);
            }
        }
        // next iteration's barA protects bstage / x2s / comb_* reuse
    }

    // per-wave loss reduce -> one global atomic per contributing wave
    if (w < 2) {
        float v = loss_local;
#pragma unroll
        for (int o = 32; o > 0; o >>= 1) v += __shfl_down(v, o);
        if (lane == 0) atomicAdd(loss_acc, v);
    }

    __syncthreads();
    if (tid < 100) {
        const unsigned c = counts_l[tid];
        if (c) atomicAdd(&counts[tid], c);
    }
}

// ---------------------------------------------------------------------------
// Finalize: greedy cluster->label assignment, exactly mirroring the reference.
// Counts loaded by 100 parallel threads (was: thread 0 serially).
// ---------------------------------------------------------------------------

__global__ void finalize_kernel(
    const float* __restrict__ loss_acc,
    const unsigned int* __restrict__ counts,
    float* __restrict__ out,
    int N)
{
    __shared__ float cs[NUM_CLASSES * NUM_CLASSES];
    __shared__ float ls;
    const int tid = threadIdx.x;
    if (tid < NUM_CLASSES * NUM_CLASSES) cs[tid] = (float)counts[tid];
    if (tid == NUM_CLASSES * NUM_CLASSES) ls = loss_acc[0];
    __syncthreads();
    if (tid == 0) {
        bool used[NUM_CLASSES];
        for (int i = 0; i < NUM_CLASSES; ++i) used[i] = false;

        float correct = 0.f;
        for (int i = 0; i < NUM_CLASSES; ++i) {
            const float* ci = cs + i * NUM_CLASSES;
            float rowsum = 0.f;
            for (int j = 0; j < NUM_CLASSES; ++j) rowsum += ci[j];
            bool has_points = rowsum > 0.f;

            int label = 0;
            float mx = ci[0];
            for (int j = 1; j < NUM_CLASSES; ++j)
                if (ci[j] > mx) { mx = ci[j]; label = j; }

            if (used[label]) {
                float mm = used[0] ? 0.f : ci[0];
                int l2 = 0;
                for (int j = 1; j < NUM_CLASSES; ++j) {
                    float v = used[j] ? 0.f : ci[j];
                    if (v > mm) { mm = v; l2 = j; }
                }
                label = l2;
            }

            if (has_points) {
                correct += ci[label];
                used[label] = true;
            }
        }
        out[0] = ls;
        out[1] = correct / (float)N;
    }
}

// ---------------------------------------------------------------------------

extern "C" void kernel_launch(void* const* d_in, const int* in_sizes, int n_in,
                              void* d_out, int out_size, void* d_ws, size_t ws_size,
                              hipStream_t stream)
{
    const float* x       = (const float*)d_in[0];
    const int*   y       = (const int*)d_in[1];
    const float* centers = (const float*)d_in[2];
    float* out = (float*)d_out;

    const int N  = in_sizes[0] / 64;  // D = 64
    const int NT = N / 128;           // 128-point tiles

    float* loss          = (float*)d_ws;                       // 4 B
    unsigned int* counts = (unsigned int*)((char*)d_ws + 4);   // 400 B

    hipMemsetAsync(d_ws, 0, 512, stream);

    int grid = 768;   // exactly 3 blocks/CU (LDS 46KB), all resident at t=0
    if (grid > NT) grid = NT;
    dist_kernel<<<grid, 512, 0, stream>>>(x, y, centers, loss, counts, NT);

    finalize_kernel<<<1, 128, 0, stream>>>(loss, counts, out, N);
}

// Round 5
// 150.493 us; speedup vs baseline: 1.5150x; 1.5150x over previous
//
#include <hip/hip_runtime.h>

#define ALPHA 0.1f
#define NUM_CLASSES 10

typedef __attribute__((ext_vector_type(8))) short bf16x8;
typedef __attribute__((ext_vector_type(4))) float f32x4;

// ---------------------------------------------------------------------------
// ws layout (bytes):
//   loss  @ 0   : float[1]
//   counts@ 4   : uint[100]
// (zeroed each launch via hipMemsetAsync)
//
// ROUND 15: R13 instruction stream (proven: 64 VGPR, zero spill, 72us)
// with occupancy/balance levers only.  R14's launch_bounds(512,6) forced a
// 40-VGPR allocation -> 114MB scratch spills -> 147us; NEVER raise min-waves
// on this kernel, never grow per-lane live state.
//  A. bstage halved to 16KB by staging each 128-pt tile in two 64-pt
//     rounds (waves 0-3 write subtiles 0-3; process; waves 4-7 overwrite
//     with subtiles 4-7; process).  LDS 46KB -> ~30KB -> 4 blocks/CU =
//     32 waves/CU (hardware max; was 24).  Barrier rate = R10's (proven
//     free).  Direct remedy for the latency-bound 47%-VALUBusy profile.
//  B. grid = 1024 = exactly 4 blocks/CU; NT=2048 -> exactly 2 tiles/block,
//     one dispatch round, zero tail (R13 ran 1024 blocks over 768 slots).
//  C. finalize: 100 threads load counts in parallel into LDS (was thread 0
//     serial: ~101 x 900cyc ~= 40us of the e2e gap).
// Numerics: identical u bits / summation order per point vs R13.
// ---------------------------------------------------------------------------

__device__ __forceinline__ unsigned pack2(float a, float b) {
    // bf16(a) lo16 | bf16(b) hi16 (truncation -> exact Dekker hi split)
    return (__float_as_uint(b) & 0xFFFF0000u) | (__float_as_uint(a) >> 16);
}
__device__ __forceinline__ float truncbf(float a) {
    return __uint_as_float(__float_as_uint(a) & 0xFFFF0000u);
}

// 512 threads = 8 waves. Wave w owns centers [w*32, w*32+32) (M dim).
// Staging: wave w converts points [t*128 + w*16, +16); waves 0-3 write the
// 16KB bstage in round A (points 0-63), waves 4-7 reuse it in round B
// (points 64-127).  Lane: r = l&15 (point row), q = l>>4 (k-group).
__global__ __launch_bounds__(512, 4) void dist_kernel(
    const float* __restrict__ x,
    const int*   __restrict__ y,
    const float* __restrict__ centers,
    float* __restrict__ loss_acc,
    unsigned int* __restrict__ counts,
    int NT)
{
    // bstage[pt][f][lane] : 16 B per lane, contiguous-lane layout (b128)
    __shared__ __align__(16) char bstage[4 * 4 * 64 * 16];   // 16 KB
    __shared__ float x2s[128];
    __shared__ float c2s[256];
    __shared__ float    comb_swe[8][128];    // 4 KB
    __shared__ float    comb_swd[8][128];    // 4 KB
    __shared__ unsigned comb_best[8][128];   // 4 KB
    __shared__ unsigned counts_l[100];

    const int tid  = threadIdx.x;
    const int w    = tid >> 6;     // wave id = center group (32 centers)
    const int lane = tid & 63;
    const int q    = lane >> 4;    // k-group
    const int r    = lane & 15;    // point row within subtile

    if (tid < 100) counts_l[tid] = 0u;

    // ---- startup: center norms (one center per thread) ----
    if (tid < 256) {
        const float4* crow = (const float4*)(centers + tid * 64);
        float s = 0.f;
#pragma unroll
        for (int j = 0; j < 16; ++j) {
            float4 v = crow[j];
            s = fmaf(v.x, v.x, s); s = fmaf(v.y, v.y, s);
            s = fmaf(v.z, v.z, s); s = fmaf(v.w, v.w, s);
        }
        c2s[tid] = s;
    }

    // ---- startup: this wave's center A-frags, PRE-SCALED by -2 ----
    // af[ct][f]; f: 0=mh k0-31, 1=mh k32-63, 2=ml k0-31, 3=ml k32-63
    bf16x8 af[2][4];
#pragma unroll
    for (int ct = 0; ct < 2; ++ct) {
        const int row = w * 32 + ct * 16 + r;
        const float4* C = (const float4*)(centers + (size_t)row * 64);
        float4 v0 = C[q * 2], v1 = C[q * 2 + 1];       // k = q*8 .. q*8+7
        float4 v2 = C[8 + q * 2], v3 = C[9 + q * 2];   // k = 32+q*8 ..
        float4 m0 = make_float4(-2.f * v0.x, -2.f * v0.y, -2.f * v0.z, -2.f * v0.w);
        float4 m1 = make_float4(-2.f * v1.x, -2.f * v1.y, -2.f * v1.z, -2.f * v1.w);
        float4 m2 = make_float4(-2.f * v2.x, -2.f * v2.y, -2.f * v2.z, -2.f * v2.w);
        float4 m3 = make_float4(-2.f * v3.x, -2.f * v3.y, -2.f * v3.z, -2.f * v3.w);
        union { bf16x8 v; unsigned u[4]; } h0, h1, l0, l1;
        h0.u[0] = pack2(m0.x, m0.y); h0.u[1] = pack2(m0.z, m0.w);
        h0.u[2] = pack2(m1.x, m1.y); h0.u[3] = pack2(m1.z, m1.w);
        h1.u[0] = pack2(m2.x, m2.y); h1.u[1] = pack2(m2.z, m2.w);
        h1.u[2] = pack2(m3.x, m3.y); h1.u[3] = pack2(m3.z, m3.w);
        l0.u[0] = pack2(m0.x - truncbf(m0.x), m0.y - truncbf(m0.y));
        l0.u[1] = pack2(m0.z - truncbf(m0.z), m0.w - truncbf(m0.w));
        l0.u[2] = pack2(m1.x - truncbf(m1.x), m1.y - truncbf(m1.y));
        l0.u[3] = pack2(m1.z - truncbf(m1.z), m1.w - truncbf(m1.w));
        l1.u[0] = pack2(m2.x - truncbf(m2.x), m2.y - truncbf(m2.y));
        l1.u[1] = pack2(m2.z - truncbf(m2.z), m2.w - truncbf(m2.w));
        l1.u[2] = pack2(m3.x - truncbf(m3.x), m3.y - truncbf(m3.y));
        l1.u[3] = pack2(m3.z - truncbf(m3.z), m3.w - truncbf(m3.w));
        af[ct][0] = h0.v; af[ct][1] = h1.v; af[ct][2] = l0.v; af[ct][3] = l1.v;
    }

    // ---- prefetch first tile's x (every wave owns one 16-pt subtile) ----
    float4 pv0, pv1, pv2, pv3;
    {
        const int row = blockIdx.x * 128 + w * 16 + r;
        const float4* X = (const float4*)(x + (size_t)row * 64);
        pv0 = X[q * 2]; pv1 = X[q * 2 + 1];
        pv2 = X[8 + q * 2]; pv3 = X[9 + q * 2];
    }

    __syncthreads();   // startup: c2s / counts_l visible

    // this lane's 8 center norms + 1: u = (x2 + c2 + 1) + (-2 x.c)
    float c2r1[2][4];
#pragma unroll
    for (int ct = 0; ct < 2; ++ct) {
        float4 v = *(const float4*)(c2s + w * 32 + ct * 16 + q * 4);
        c2r1[ct][0] = v.x + 1.f; c2r1[ct][1] = v.y + 1.f;
        c2r1[ct][2] = v.z + 1.f; c2r1[ct][3] = v.w + 1.f;
    }

    float loss_local = 0.f;

    for (int t = blockIdx.x; t < NT; t += gridDim.x) {
        // ---- y prefetch for this tile's combine (latency spans the tile) ----
        int ylab = 0;
        if (tid < 128) ylab = y[t * 128 + tid];
        const int tn = t + gridDim.x;

        // ================= round A: waves 0-3 stage points 0-63 ============
        if (w < 4) {
            float4 v0 = pv0, v1 = pv1, v2 = pv2, v3 = pv3;
            if (tn < NT) {   // issue next tile's loads immediately
                const int row = tn * 128 + w * 16 + r;
                const float4* X = (const float4*)(x + (size_t)row * 64);
                pv0 = X[q * 2]; pv1 = X[q * 2 + 1];
                pv2 = X[8 + q * 2]; pv3 = X[9 + q * 2];
            }

            float p = v0.x * v0.x;
            p = fmaf(v0.y, v0.y, p); p = fmaf(v0.z, v0.z, p); p = fmaf(v0.w, v0.w, p);
            p = fmaf(v1.x, v1.x, p); p = fmaf(v1.y, v1.y, p); p = fmaf(v1.z, v1.z, p); p = fmaf(v1.w, v1.w, p);
            p = fmaf(v2.x, v2.x, p); p = fmaf(v2.y, v2.y, p); p = fmaf(v2.z, v2.z, p); p = fmaf(v2.w, v2.w, p);
            p = fmaf(v3.x, v3.x, p); p = fmaf(v3.y, v3.y, p); p = fmaf(v3.z, v3.z, p); p = fmaf(v3.w, v3.w, p);
            p += __shfl_xor(p, 16);
            p += __shfl_xor(p, 32);
            if (q == 0) x2s[w * 16 + r] = p;

            union { bf16x8 v; uint4 u4; unsigned u[4]; } h0, h1, l0, l1;
            h0.u[0] = pack2(v0.x, v0.y); h0.u[1] = pack2(v0.z, v0.w);
            h0.u[2] = pack2(v1.x, v1.y); h0.u[3] = pack2(v1.z, v1.w);
            h1.u[0] = pack2(v2.x, v2.y); h1.u[1] = pack2(v2.z, v2.w);
            h1.u[2] = pack2(v3.x, v3.y); h1.u[3] = pack2(v3.z, v3.w);
            l0.u[0] = pack2(v0.x - truncbf(v0.x), v0.y - truncbf(v0.y));
            l0.u[1] = pack2(v0.z - truncbf(v0.z), v0.w - truncbf(v0.w));
            l0.u[2] = pack2(v1.x - truncbf(v1.x), v1.y - truncbf(v1.y));
            l0.u[3] = pack2(v1.z - truncbf(v1.z), v1.w - truncbf(v1.w));
            l1.u[0] = pack2(v2.x - truncbf(v2.x), v2.y - truncbf(v2.y));
            l1.u[1] = pack2(v2.z - truncbf(v2.z), v2.w - truncbf(v2.w));
            l1.u[2] = pack2(v3.x - truncbf(v3.x), v3.y - truncbf(v3.y));
            l1.u[3] = pack2(v3.z - truncbf(v3.z), v3.w - truncbf(v3.w));
            *(uint4*)(bstage + (((w * 4 + 0) * 64 + lane) << 4)) = h0.u4;
            *(uint4*)(bstage + (((w * 4 + 1) * 64 + lane) << 4)) = h1.u4;
            *(uint4*)(bstage + (((w * 4 + 2) * 64 + lane) << 4)) = l0.u4;
            *(uint4*)(bstage + (((w * 4 + 3) * 64 + lane) << 4)) = l1.u4;
        }
        __syncthreads();   // s1: A-half frags + x2s[0:64] visible; prev combine done

        // ---- pts 0-3 (points 0-63) ----
#pragma unroll
        for (int pt = 0; pt < 4; ++pt) {
            union { uint4 u4; bf16x8 v; } b0, b1, b2, b3;
            b0.u4 = *(const uint4*)(bstage + (((pt * 4 + 0) * 64 + lane) << 4));
            b1.u4 = *(const uint4*)(bstage + (((pt * 4 + 1) * 64 + lane) << 4));
            b2.u4 = *(const uint4*)(bstage + (((pt * 4 + 2) * 64 + lane) << 4));
            b3.u4 = *(const uint4*)(bstage + (((pt * 4 + 3) * 64 + lane) << 4));
            const float x2p = x2s[pt * 16 + r];

            f32x4 acc[2];
#pragma unroll
            for (int ct = 0; ct < 2; ++ct) {
                f32x4 a;
                a[0] = x2p + c2r1[ct][0]; a[1] = x2p + c2r1[ct][1];
                a[2] = x2p + c2r1[ct][2]; a[3] = x2p + c2r1[ct][3];
                a = __builtin_amdgcn_mfma_f32_16x16x32_bf16(af[ct][0], b0.v, a, 0, 0, 0); // mh.xh
                a = __builtin_amdgcn_mfma_f32_16x16x32_bf16(af[ct][1], b1.v, a, 0, 0, 0);
                a = __builtin_amdgcn_mfma_f32_16x16x32_bf16(af[ct][2], b0.v, a, 0, 0, 0); // ml.xh
                a = __builtin_amdgcn_mfma_f32_16x16x32_bf16(af[ct][3], b1.v, a, 0, 0, 0);
                a = __builtin_amdgcn_mfma_f32_16x16x32_bf16(af[ct][0], b2.v, a, 0, 0, 0); // mh.xl
                a = __builtin_amdgcn_mfma_f32_16x16x32_bf16(af[ct][1], b3.v, a, 0, 0, 0);
                acc[ct] = a;
            }

            float swe = 0.f, swdu = 0.f;
            unsigned best = 0xFFFFFFFFu;
#pragma unroll
            for (int ct = 0; ct < 2; ++ct) {
#pragma unroll
                for (int reg = 0; reg < 4; ++reg) {
                    const float u = acc[ct][reg];          // u = 1 + d
                    const unsigned kid = (unsigned)(w * 32 + ct * 16 + q * 4 + reg);
                    best = min(best, (__float_as_uint(u) & 0xFFFFFF00u) | kid);
                    float wg = exp2f(-ALPHA * __log2f(u));
                    swe += wg;
                    swdu = fmaf(wg, u, swdu);
                }
            }
            swe += __shfl_xor(swe, 16); swe += __shfl_xor(swe, 32);
            swdu += __shfl_xor(swdu, 16); swdu += __shfl_xor(swdu, 32);
            best = min(best, (unsigned)__shfl_xor((int)best, 16));
            best = min(best, (unsigned)__shfl_xor((int)best, 32));
            if (q == 0) {
                comb_swe[w][pt * 16 + r]  = swe;
                comb_swd[w][pt * 16 + r]  = swdu;
                comb_best[w][pt * 16 + r] = best;
            }
        }
        __syncthreads();   // s2: A-half bstage reads done

        // ================= round B: waves 4-7 stage points 64-127 ==========
        if (w >= 4) {
            float4 v0 = pv0, v1 = pv1, v2 = pv2, v3 = pv3;
            if (tn < NT) {
                const int row = tn * 128 + w * 16 + r;
                const float4* X = (const float4*)(x + (size_t)row * 64);
                pv0 = X[q * 2]; pv1 = X[q * 2 + 1];
                pv2 = X[8 + q * 2]; pv3 = X[9 + q * 2];
            }

            float p = v0.x * v0.x;
            p = fmaf(v0.y, v0.y, p); p = fmaf(v0.z, v0.z, p); p = fmaf(v0.w, v0.w, p);
            p = fmaf(v1.x, v1.x, p); p = fmaf(v1.y, v1.y, p); p = fmaf(v1.z, v1.z, p); p = fmaf(v1.w, v1.w, p);
            p = fmaf(v2.x, v2.x, p); p = fmaf(v2.y, v2.y, p); p = fmaf(v2.z, v2.z, p); p = fmaf(v2.w, v2.w, p);
            p = fmaf(v3.x, v3.x, p); p = fmaf(v3.y, v3.y, p); p = fmaf(v3.z, v3.z, p); p = fmaf(v3.w, v3.w, p);
            p += __shfl_xor(p, 16);
            p += __shfl_xor(p, 32);
            if (q == 0) x2s[w * 16 + r] = p;

            union { bf16x8 v; uint4 u4; unsigned u[4]; } h0, h1, l0, l1;
            h0.u[0] = pack2(v0.x, v0.y); h0.u[1] = pack2(v0.z, v0.w);
            h0.u[2] = pack2(v1.x, v1.y); h0.u[3] = pack2(v1.z, v1.w);
            h1.u[0] = pack2(v2.x, v2.y); h1.u[1] = pack2(v2.z, v2.w);
            h1.u[2] = pack2(v3.x, v3.y); h1.u[3] = pack2(v3.z, v3.w);
            l0.u[0] = pack2(v0.x - truncbf(v0.x), v0.y - truncbf(v0.y));
            l0.u[1] = pack2(v0.z - truncbf(v0.z), v0.w - truncbf(v0.w));
            l0.u[2] = pack2(v1.x - truncbf(v1.x), v1.y - truncbf(v1.y));
            l0.u[3] = pack2(v1.z - truncbf(v1.z), v1.w - truncbf(v1.w));
            l1.u[0] = pack2(v2.x - truncbf(v2.x), v2.y - truncbf(v2.y));
            l1.u[1] = pack2(v2.z - truncbf(v2.z), v2.w - truncbf(v2.w));
            l1.u[2] = pack2(v3.x - truncbf(v3.x), v3.y - truncbf(v3.y));
            l1.u[3] = pack2(v3.z - truncbf(v3.z), v3.w - truncbf(v3.w));
            *(uint4*)(bstage + ((((w - 4) * 4 + 0) * 64 + lane) << 4)) = h0.u4;
            *(uint4*)(bstage + ((((w - 4) * 4 + 1) * 64 + lane) << 4)) = h1.u4;
            *(uint4*)(bstage + ((((w - 4) * 4 + 2) * 64 + lane) << 4)) = l0.u4;
            *(uint4*)(bstage + ((((w - 4) * 4 + 3) * 64 + lane) << 4)) = l1.u4;
        }
        __syncthreads();   // s3: B-half frags + x2s[64:128] visible

        // ---- pts 4-7 (points 64-127) ----
#pragma unroll
        for (int pt = 0; pt < 4; ++pt) {
            union { uint4 u4; bf16x8 v; } b0, b1, b2, b3;
            b0.u4 = *(const uint4*)(bstage + (((pt * 4 + 0) * 64 + lane) << 4));
            b1.u4 = *(const uint4*)(bstage + (((pt * 4 + 1) * 64 + lane) << 4));
            b2.u4 = *(const uint4*)(bstage + (((pt * 4 + 2) * 64 + lane) << 4));
            b3.u4 = *(const uint4*)(bstage + (((pt * 4 + 3) * 64 + lane) << 4));
            const float x2p = x2s[64 + pt * 16 + r];

            f32x4 acc[2];
#pragma unroll
            for (int ct = 0; ct < 2; ++ct) {
                f32x4 a;
                a[0] = x2p + c2r1[ct][0]; a[1] = x2p + c2r1[ct][1];
                a[2] = x2p + c2r1[ct][2]; a[3] = x2p + c2r1[ct][3];
                a = __builtin_amdgcn_mfma_f32_16x16x32_bf16(af[ct][0], b0.v, a, 0, 0, 0); // mh.xh
                a = __builtin_amdgcn_mfma_f32_16x16x32_bf16(af[ct][1], b1.v, a, 0, 0, 0);
                a = __builtin_amdgcn_mfma_f32_16x16x32_bf16(af[ct][2], b0.v, a, 0, 0, 0); // ml.xh
                a = __builtin_amdgcn_mfma_f32_16x16x32_bf16(af[ct][3], b1.v, a, 0, 0, 0);
                a = __builtin_amdgcn_mfma_f32_16x16x32_bf16(af[ct][0], b2.v, a, 0, 0, 0); // mh.xl
                a = __builtin_amdgcn_mfma_f32_16x16x32_bf16(af[ct][1], b3.v, a, 0, 0, 0);
                acc[ct] = a;
            }

            float swe = 0.f, swdu = 0.f;
            unsigned best = 0xFFFFFFFFu;
#pragma unroll
            for (int ct = 0; ct < 2; ++ct) {
#pragma unroll
                for (int reg = 0; reg < 4; ++reg) {
                    const float u = acc[ct][reg];          // u = 1 + d
                    const unsigned kid = (unsigned)(w * 32 + ct * 16 + q * 4 + reg);
                    best = min(best, (__float_as_uint(u) & 0xFFFFFF00u) | kid);
                    float wg = exp2f(-ALPHA * __log2f(u));
                    swe += wg;
                    swdu = fmaf(wg, u, swdu);
                }
            }
            swe += __shfl_xor(swe, 16); swe += __shfl_xor(swe, 32);
            swdu += __shfl_xor(swdu, 16); swdu += __shfl_xor(swdu, 32);
            best = min(best, (unsigned)__shfl_xor((int)best, 16));
            best = min(best, (unsigned)__shfl_xor((int)best, 32));
            if (q == 0) {
                comb_swe[w][64 + pt * 16 + r]  = swe;
                comb_swd[w][64 + pt * 16 + r]  = swdu;
                comb_best[w][64 + pt * 16 + r] = best;
            }
        }
        __syncthreads();   // s4: all partials visible

        // ---- combine across 8 center groups (waves 0-1, one point each) ----
        if (tid < 128) {
            float SWE = comb_swe[0][tid], SWD = comb_swd[0][tid];
            unsigned BEST = comb_best[0][tid];
#pragma unroll
            for (int g = 1; g < 8; ++g) {
                SWE += comb_swe[g][tid];
                SWD += comb_swd[g][tid];
                BEST = min(BEST, comb_best[g][tid]);
            }
            loss_local += SWD / SWE - 1.f;   // Sum w*d / Sum w  ==  swdu/swe - 1
            const unsigned bk = BEST & 0xFFu;
            if (bk < NUM_CLASSES) {
                atomicAdd(&counts_l[bk * NUM_CLASSES + ylab], 1u);
            }
        }
        // next iteration's s1 protects bstage / x2s / comb_* reuse
    }

    // per-wave loss reduce -> one global atomic per contributing wave
    if (w < 2) {
        float v = loss_local;
#pragma unroll
        for (int o = 32; o > 0; o >>= 1) v += __shfl_down(v, o);
        if (lane == 0) atomicAdd(loss_acc, v);
    }

    __syncthreads();
    if (tid < 100) {
        const unsigned c = counts_l[tid];
        if (c) atomicAdd(&counts[tid], c);
    }
}

// ---------------------------------------------------------------------------
// Finalize: greedy cluster->label assignment, exactly mirroring the reference.
// Counts loaded by 100 parallel threads (was: thread 0 serially, ~40us).
// ---------------------------------------------------------------------------

__global__ void finalize_kernel(
    const float* __restrict__ loss_acc,
    const unsigned int* __restrict__ counts,
    float* __restrict__ out,
    int N)
{
    __shared__ float cs[NUM_CLASSES * NUM_CLASSES];
    __shared__ float ls;
    const int tid = threadIdx.x;
    if (tid < NUM_CLASSES * NUM_CLASSES) cs[tid] = (float)counts[tid];
    if (tid == NUM_CLASSES * NUM_CLASSES) ls = loss_acc[0];
    __syncthreads();
    if (tid == 0) {
        bool used[NUM_CLASSES];
        for (int i = 0; i < NUM_CLASSES; ++i) used[i] = false;

        float correct = 0.f;
        for (int i = 0; i < NUM_CLASSES; ++i) {
            const float* ci = cs + i * NUM_CLASSES;
            float rowsum = 0.f;
            for (int j = 0; j < NUM_CLASSES; ++j) rowsum += ci[j];
            bool has_points = rowsum > 0.f;

            int label = 0;
            float mx = ci[0];
            for (int j = 1; j < NUM_CLASSES; ++j)
                if (ci[j] > mx) { mx = ci[j]; label = j; }

            if (used[label]) {
                float mm = used[0] ? 0.f : ci[0];
                int l2 = 0;
                for (int j = 1; j < NUM_CLASSES; ++j) {
                    float v = used[j] ? 0.f : ci[j];
                    if (v > mm) { mm = v; l2 = j; }
                }
                label = l2;
            }

            if (has_points) {
                correct += ci[label];
                used[label] = true;
            }
        }
        out[0] = ls;
        out[1] = correct / (float)N;
    }
}

// ---------------------------------------------------------------------------

extern "C" void kernel_launch(void* const* d_in, const int* in_sizes, int n_in,
                              void* d_out, int out_size, void* d_ws, size_t ws_size,
                              hipStream_t stream)
{
    const float* x       = (const float*)d_in[0];
    const int*   y       = (const int*)d_in[1];
    const float* centers = (const float*)d_in[2];
    float* out = (float*)d_out;

    const int N  = in_sizes[0] / 64;  // D = 64
    const int NT = N / 128;           // 128-point tiles

    float* loss          = (float*)d_ws;                       // 4 B
    unsigned int* counts = (unsigned int*)((char*)d_ws + 4);   // 400 B

    hipMemsetAsync(d_ws, 0, 512, stream);

    int grid = 1024;  // exactly 4 blocks/CU (LDS ~30KB, 32 waves/CU max); 2 tiles/block
    if (grid > NT) grid = NT;
    dist_kernel<<<grid, 512, 0, stream>>>(x, y, centers, loss, counts, NT);

    finalize_kernel<<<1, 128, 0, stream>>>(loss, counts, out, N);
}